// Round 6
// baseline (466.281 us; speedup 1.0000x reference)
//
#include <hip/hip_runtime.h>
#include <math.h>

typedef unsigned short u16;
typedef unsigned int   u32;

#define SS_    4
#define NH     4
#define Dh     32
#define Cdim   128
#define Ntok   64
#define WTOT   2048
#define Mrows  131072   // WTOT * Ntok
#define HIDDEN 512
#define PSTR   72       // attn P LDS row stride (u16)
#define OSTR   136      // attn Osm row stride (u16): 272 B, 16-B aligned
#define HPAD   136      // LDS row stride (u16): 272 B, 16-B aligned

typedef __bf16 bf16x8 __attribute__((ext_vector_type(8)));
typedef u16    u16x8  __attribute__((ext_vector_type(8)));
typedef float  f32x4  __attribute__((ext_vector_type(4)));

__device__ __forceinline__ float bf2f(u16 u){
    union {u32 i; float f;} v; v.i = ((u32)u) << 16; return v.f;
}
__device__ __forceinline__ u16 f2bf(float f){
    union {float f; u32 i;} v; v.f = f;
    u32 x = v.i;
    return (u16)((x + 0x7fffu + ((x >> 16) & 1u)) >> 16);
}

// GELU with A&S 7.1.26 erf approx (max err 1.5e-7)
__device__ __forceinline__ float fast_gelu(float v){
    float a = v * 0.70710678118654752f;
    float x = fabsf(a);
    float t = 1.0f / (1.0f + 0.3275911f * x);
    float p = ((((1.061405429f*t - 1.453152027f)*t + 1.421413741f)*t
                - 0.284496736f)*t + 0.254829592f)*t;
    float e = __expf(-x*x);
    float er = copysignf(1.0f - p*e, a);
    return 0.5f * v * (1.0f + er);
}

// token (windowed row) -> original token index (bijection, shift +4 both dims)
__device__ __forceinline__ int map_row_to_token(int r){
    int w = r >> 6, n = r & 63;
    int b = w >> 8, win = w & 255;
    int wy = win >> 4, wx = win & 15;
    int iy = n >> 3, ix = n & 7;
    int ro = (wy*8 + iy + SS_) & 127;
    int co = (wx*8 + ix + SS_) & 127;
    return (b << 14) + (ro << 7) + co;
}

// token index -> windowed row (inverse map)
__device__ __forceinline__ int map_token_to_row(int t){
    int b = t >> 14, ro = (t >> 7) & 127, co = t & 127;
    int y  = (ro + 128 - SS_) & 127;
    int xq = (co + 128 - SS_) & 127;
    return (((b << 8) | ((y >> 3) << 4) | (xq >> 3)) << 6) + (y & 7)*8 + (xq & 7);
}

// ---------------- fp32 -> bf16 weight conversion ----------------
__global__ void __launch_bounds__(256) cvt_kernel(const float* __restrict__ src,
        u16* __restrict__ dst, int n)
{
    int i = blockIdx.x * 256 + threadIdx.x;
    if (i < n) dst[i] = f2bf(src[i]);
}

// ---------------- bias+mask table: bm[cls][h][row][col], 4*4*64*64 fp32 ----------
__global__ void __launch_bounds__(256) bm_kernel(const float* __restrict__ rpb,
        float* __restrict__ bmt)
{
    int e = blockIdx.x * 256 + threadIdx.x;     // 65536 total
    int cls = e >> 14, h = (e >> 12) & 3, row = (e >> 6) & 63, col = e & 63;
    int iy = row >> 3, ix = row & 7, jy = col >> 3, jx = col & 7;
    int bidx = (iy - jy + 7)*15 + (ix - jx + 7);
    float bias = rpb[bidx*NH + h];
    int ybit = cls >> 1, xbit = cls & 1;
    int ri = (ybit ? (iy < 4 ? 1 : 2) : 0)*3 + (xbit ? (ix < 4 ? 1 : 2) : 0);
    int rj = (ybit ? (jy < 4 ? 1 : 2) : 0)*3 + (xbit ? (jx < 4 ? 1 : 2) : 0);
    bmt[e] = bias + ((ri != rj) ? -100.0f : 0.0f);
}

// ---- Fused LN1 + QKV GEMM: block (which, tile). Stage 128x128 LN1'd bf16 tile
// in LDS (windowed gather from x), then 4-wave 2x2 MFMA GEMM over the 128 cols
// of q/k/v selected by `which`. Grid (3, 1024), x-fastest: the 3 blocks of one
// tile stage the same x rows back-to-back (L2-hot). Eliminates ln1out.
__global__ void __launch_bounds__(256, 4) ln1qkv_kernel(
        const float* __restrict__ x,
        const float* __restrict__ g, const float* __restrict__ bsh,
        const u16* __restrict__ Bw,      // qkvw_b [384][128]
        const float* __restrict__ bias,  // qkvb [384]
        u16* __restrict__ qb, u16* __restrict__ kb, u16* __restrict__ vb)
{
    __shared__ __align__(16) u16 Asm[128*HPAD];   // 34816 B
    int t = threadIdx.x;
    int which = blockIdx.x;                       // 0=q 1=k 2=v
    size_t tilebase = (size_t)blockIdx.y * 128;

    // stage: LN1 over each windowed row (16-lane group owns one row)
    #pragma unroll
    for (int it = 0; it < 8; it++){
        int idx = it*256 + t;
        int r   = idx >> 4, c8 = idx & 15;
        int trow = (int)tilebase + r;
        int src  = map_row_to_token(trow);
        f32x4 xa = *(const f32x4*)&x[(size_t)src*Cdim + c8*8];
        f32x4 xb = *(const f32x4*)&x[(size_t)src*Cdim + c8*8 + 4];
        float s = 0.0f, s2 = 0.0f;
        #pragma unroll
        for (int k = 0; k < 4; k++){
            s += xa[k] + xb[k];
            s2 += xa[k]*xa[k] + xb[k]*xb[k];
        }
        #pragma unroll
        for (int off = 1; off <= 8; off <<= 1){
            s  += __shfl_xor(s,  off, 64);
            s2 += __shfl_xor(s2, off, 64);
        }
        float mean = s * (1.0f/128.0f);
        float var  = s2 * (1.0f/128.0f) - mean*mean;
        float inv  = rsqrtf(var + 1e-5f);
        f32x4 ga = *(const f32x4*)&g[c8*8],  gb = *(const f32x4*)&g[c8*8 + 4];
        f32x4 ba = *(const f32x4*)&bsh[c8*8], bb = *(const f32x4*)&bsh[c8*8 + 4];
        u16x8 ov;
        #pragma unroll
        for (int k = 0; k < 4; k++){
            ov[k]   = f2bf((xa[k] - mean) * inv * ga[k] + ba[k]);
            ov[k+4] = f2bf((xb[k] - mean) * inv * gb[k] + bb[k]);
        }
        *(u16x8*)&Asm[r*HPAD + c8*8] = ov;
    }
    __syncthreads();

    int wave = t >> 6, lane = t & 63;
    int wr = wave & 1, wc = wave >> 1;
    int m = lane & 15, quad = lane >> 4;

    f32x4 acc[4][4] = {};
    #pragma unroll
    for (int s = 0; s < 4; s++){
        bf16x8 aq[4], bk[4];
        #pragma unroll
        for (int i = 0; i < 4; i++)
            aq[i] = *(const bf16x8*)&Asm[(wr*64 + i*16 + m)*HPAD + s*32 + quad*8];
        #pragma unroll
        for (int j = 0; j < 4; j++)
            bk[j] = *(const bf16x8*)&Bw[(size_t)(which*128 + wc*64 + j*16 + m)*Cdim
                                        + s*32 + quad*8];
        #pragma unroll
        for (int i = 0; i < 4; i++)
            #pragma unroll
            for (int j = 0; j < 4; j++)
                acc[i][j] = __builtin_amdgcn_mfma_f32_16x16x32_bf16(
                                aq[i], bk[j], acc[i][j], 0, 0, 0);
    }

    // qkv scatter epilogue (q scaled, k normal, v transposed [w][h][d][n])
    #pragma unroll
    for (int i = 0; i < 4; i++){
        #pragma unroll
        for (int j = 0; j < 4; j++){
            int c = which*128 + wc*64 + j*16 + m;
            float bia = bias[c];
            int h = (c >> 5) & 3;
            int d = c & 31;
            #pragma unroll
            for (int rg = 0; rg < 4; rg++){
                int r = (int)tilebase + wr*64 + i*16 + quad*4 + rg;
                float v = acc[i][j][rg] + bia;
                int w = r >> 6, n = r & 63;
                if (which == 0){
                    qb[((size_t)(w*NH + h)*Ntok + n)*Dh + d] =
                        f2bf(v * 0.17677669529663687f);
                } else if (which == 1){
                    kb[((size_t)(w*NH + h)*Ntok + n)*Dh + d] = f2bf(v);
                } else {
                    vb[((size_t)(w*NH + h)*Dh + d)*Ntok + n] = f2bf(v);
                }
            }
        }
    }
}

// --- Fused residual + LN2 + MLP, 64-row tiles for 4 blocks/CU:
//   out = (x + proj~) + GELU(LN2(x + proj~) @ W1^T + b1) @ W2^T + b2
// 2048 blocks x 256 threads (4 waves, 2x2 over the 64x128 out tile).
__global__ void __launch_bounds__(256, 4) mlp_kernel(
        const float* __restrict__ x,     // [Mrows][128] fp32, token order
        const u16* __restrict__ projout, // [Mrows][128] bf16, windowed order
        const float* __restrict__ g, const float* __restrict__ bsh,
        const u16* __restrict__ W1,      // fc1w [512][128] bf16
        const float* __restrict__ b1,
        const u16* __restrict__ W2,      // fc2w [128][512] bf16
        const float* __restrict__ b2,
        float* __restrict__ outp)        // out  [Mrows][128] fp32
{
    __shared__ __align__(16) u16 Asm[64*HPAD];    // 17408 B
    __shared__ __align__(16) u16 Hsm[64*HPAD];    // 17408 B
    int t = threadIdx.x;
    int wave = t >> 6, lane = t & 63;
    int wr = wave & 1, wc = wave >> 1;
    int m = lane & 15, quad = lane >> 4;
    size_t rowbase = (size_t)blockIdx.x * 64;

    // ---- fused stage: val = x + proj~, LN2 -> bf16 Asm tile (64 rows) ----
    #pragma unroll
    for (int it = 0; it < 4; it++){
        int idx  = it*256 + t;
        int r    = idx >> 4, c8 = idx & 15;
        int trow = (int)rowbase + r;
        int rr   = map_token_to_row(trow);
        f32x4 xa = *(const f32x4*)&x[(size_t)trow*Cdim + c8*8];
        f32x4 xb = *(const f32x4*)&x[(size_t)trow*Cdim + c8*8 + 4];
        u16x8 pv = *(const u16x8*)&projout[(size_t)rr*Cdim + c8*8];
        float val[8];
        float s = 0.0f, s2 = 0.0f;
        #pragma unroll
        for (int k = 0; k < 8; k++){
            float xv = (k < 4) ? xa[k] : xb[k-4];
            val[k] = xv + bf2f(pv[k]);
            s += val[k]; s2 += val[k]*val[k];
        }
        #pragma unroll
        for (int off = 1; off <= 8; off <<= 1){
            s  += __shfl_xor(s,  off, 64);
            s2 += __shfl_xor(s2, off, 64);
        }
        float mean = s * (1.0f/128.0f);
        float var  = s2 * (1.0f/128.0f) - mean*mean;
        float inv  = rsqrtf(var + 1e-5f);
        f32x4 ga = *(const f32x4*)&g[c8*8],  gb = *(const f32x4*)&g[c8*8 + 4];
        f32x4 ba = *(const f32x4*)&bsh[c8*8], bb = *(const f32x4*)&bsh[c8*8 + 4];
        u16x8 ov;
        #pragma unroll
        for (int k = 0; k < 8; k++){
            float gv = (k < 4) ? ga[k] : gb[k-4];
            float bv = (k < 4) ? ba[k] : bb[k-4];
            ov[k] = f2bf((val[k] - mean) * inv * gv + bv);
        }
        *(u16x8*)&Asm[r*HPAD + c8*8] = ov;
    }
    __syncthreads();

    f32x4 O[2][4] = {};                  // 32 rows x 64 out cols per wave

    for (int kk = 0; kk < 4; kk++){
        // ---- H chunk: Hc = GELU(A @ W1[kk*128 ..][:]^T + b1) ----
        f32x4 Hacc[2][4] = {};
        #pragma unroll
        for (int s = 0; s < 4; s++){
            bf16x8 aq[2], bk[4];
            #pragma unroll
            for (int i = 0; i < 2; i++)
                aq[i] = *(const bf16x8*)&Asm[(wr*32 + i*16 + m)*HPAD + s*32 + quad*8];
            #pragma unroll
            for (int j = 0; j < 4; j++)
                bk[j] = *(const bf16x8*)&W1[(size_t)(kk*128 + wc*64 + j*16 + m)*Cdim
                                            + s*32 + quad*8];
            #pragma unroll
            for (int i = 0; i < 2; i++)
                #pragma unroll
                for (int j = 0; j < 4; j++)
                    Hacc[i][j] = __builtin_amdgcn_mfma_f32_16x16x32_bf16(
                                     aq[i], bk[j], Hacc[i][j], 0, 0, 0);
        }
        #pragma unroll
        for (int i = 0; i < 2; i++){
            #pragma unroll
            for (int j = 0; j < 4; j++){
                int hc = wc*64 + j*16 + m;          // hidden col within chunk
                float bia = b1[kk*128 + hc];
                #pragma unroll
                for (int rg = 0; rg < 4; rg++){
                    int r = wr*32 + i*16 + quad*4 + rg;
                    Hsm[r*HPAD + hc] = f2bf(fast_gelu(Hacc[i][j][rg] + bia));
                }
            }
        }
        __syncthreads();

        // ---- O += Hc @ W2[:, kk*128 ..]^T ----
        #pragma unroll
        for (int s = 0; s < 4; s++){
            bf16x8 pa[2], bk[4];
            #pragma unroll
            for (int i = 0; i < 2; i++)
                pa[i] = *(const bf16x8*)&Hsm[(wr*32 + i*16 + m)*HPAD + s*32 + quad*8];
            #pragma unroll
            for (int j = 0; j < 4; j++)
                bk[j] = *(const bf16x8*)&W2[(size_t)(wc*64 + j*16 + m)*HIDDEN
                                            + kk*128 + s*32 + quad*8];
            #pragma unroll
            for (int i = 0; i < 2; i++)
                #pragma unroll
                for (int j = 0; j < 4; j++)
                    O[i][j] = __builtin_amdgcn_mfma_f32_16x16x32_bf16(
                                  pa[i], bk[j], O[i][j], 0, 0, 0);
        }
        __syncthreads();   // Hsm reused next chunk
    }

    // ---- epilogue: out = (x + proj~) + O + b2 (x/proj re-read; L2-hot) ----
    #pragma unroll
    for (int i = 0; i < 2; i++){
        #pragma unroll
        for (int rg = 0; rg < 4; rg++){
            int r  = (int)rowbase + wr*32 + i*16 + quad*4 + rg;   // token row
            int rr = map_token_to_row(r);
            #pragma unroll
            for (int j = 0; j < 4; j++){
                int c = wc*64 + j*16 + m;
                float v = x[(size_t)r*Cdim + c] + bf2f(projout[(size_t)rr*Cdim + c])
                          + O[i][j][rg] + b2[c];
                outp[(size_t)r*Cdim + c] = v;
            }
        }
    }
}

// ------- Fused attention + proj: block = window, wave = head -------------------
__global__ void __launch_bounds__(256) attnproj_kernel(
        const u16* __restrict__ qb, const u16* __restrict__ kb,
        const u16* __restrict__ vt, const float* __restrict__ bmt,
        const u16* __restrict__ pw, const float* __restrict__ pb,
        u16* __restrict__ projout)
{
    __shared__ __align__(16) u16 SH[NH*64*PSTR];   // 36864 B; P + (union) Osm
    int w = blockIdx.x;
    int win = w & 255;
    int wy = win >> 4, wx = win & 15;
    int cls = ((wy == 15) ? 2 : 0) | ((wx == 15) ? 1 : 0);
    int t = threadIdx.x;
    int h = t >> 6, lane = t & 63;
    int m = lane & 15, quad = lane >> 4;
    u16* Ph  = SH + h*64*PSTR;     // per-wave private P rows
    u16* Osm = SH;                 // 64 x OSTR union view (after barrier 1)

    const u16* qg = qb + (size_t)(w*NH + h)*2048;   // [n][d]
    const u16* kg = kb + (size_t)(w*NH + h)*2048;   // [n][d]
    const u16* vg = vt + (size_t)(w*NH + h)*2048;   // [d][n] (transposed)
    const float* bm = bmt + (size_t)(cls*NH + h)*4096;

    // S = Q @ K^T  (64x64, one K=32 step)
    bf16x8 aq[4], bk[4];
    #pragma unroll
    for (int i = 0; i < 4; i++)
        aq[i] = *(const bf16x8*)&qg[(i*16 + m)*32 + quad*8];
    #pragma unroll
    for (int j = 0; j < 4; j++)
        bk[j] = *(const bf16x8*)&kg[(j*16 + m)*32 + quad*8];
    f32x4 S[4][4] = {};
    #pragma unroll
    for (int i = 0; i < 4; i++)
        #pragma unroll
        for (int j = 0; j < 4; j++)
            S[i][j] = __builtin_amdgcn_mfma_f32_16x16x32_bf16(
                          aq[i], bk[j], S[i][j], 0, 0, 0);

    // bias+mask add, row softmax -> P (bf16, per-wave private; no barrier)
    #pragma unroll
    for (int i = 0; i < 4; i++){
        #pragma unroll
        for (int rg = 0; rg < 4; rg++){
            int row = i*16 + quad*4 + rg;
            float s0 = S[i][0][rg] + bm[row*64 +  0 + m];
            float s1 = S[i][1][rg] + bm[row*64 + 16 + m];
            float s2 = S[i][2][rg] + bm[row*64 + 32 + m];
            float s3 = S[i][3][rg] + bm[row*64 + 48 + m];
            float mx = fmaxf(fmaxf(s0, s1), fmaxf(s2, s3));
            mx = fmaxf(mx, __shfl_xor(mx, 1, 64));
            mx = fmaxf(mx, __shfl_xor(mx, 2, 64));
            mx = fmaxf(mx, __shfl_xor(mx, 4, 64));
            mx = fmaxf(mx, __shfl_xor(mx, 8, 64));
            s0 = __expf(s0 - mx); s1 = __expf(s1 - mx);
            s2 = __expf(s2 - mx); s3 = __expf(s3 - mx);
            float sm = s0 + s1 + s2 + s3;
            sm += __shfl_xor(sm, 1, 64);
            sm += __shfl_xor(sm, 2, 64);
            sm += __shfl_xor(sm, 4, 64);
            sm += __shfl_xor(sm, 8, 64);
            float rinv = 1.0f / sm;
            u16* pr = &Ph[row*PSTR];
            pr[ 0 + m] = f2bf(s0 * rinv);
            pr[16 + m] = f2bf(s1 * rinv);
            pr[32 + m] = f2bf(s2 * rinv);
            pr[48 + m] = f2bf(s3 * rinv);
        }
    }

    // O = P @ V  (64x32, two K=32 steps)
    f32x4 O[4][2] = {};
    #pragma unroll
    for (int s2 = 0; s2 < 2; s2++){
        bf16x8 pa[4], bv[2];
        #pragma unroll
        for (int i = 0; i < 4; i++)
            pa[i] = *(const bf16x8*)&Ph[(i*16 + m)*PSTR + s2*32 + quad*8];
        #pragma unroll
        for (int dt = 0; dt < 2; dt++)
            bv[dt] = *(const bf16x8*)&vg[(dt*16 + m)*64 + s2*32 + quad*8];
        #pragma unroll
        for (int i = 0; i < 4; i++)
            #pragma unroll
            for (int dt = 0; dt < 2; dt++)
                O[i][dt] = __builtin_amdgcn_mfma_f32_16x16x32_bf16(
                               pa[i], bv[dt], O[i][dt], 0, 0, 0);
    }

    __syncthreads();   // all P reads done; SH is reused as Osm below

    // stage head-concat tile: Osm[row][h*32 + dt*16 + m]
    #pragma unroll
    for (int i = 0; i < 4; i++)
        #pragma unroll
        for (int dt = 0; dt < 2; dt++)
            #pragma unroll
            for (int rg = 0; rg < 4; rg++)
                Osm[(i*16 + quad*4 + rg)*OSTR + h*Dh + dt*16 + m] =
                    f2bf(O[i][dt][rg]);
    __syncthreads();

    // proj GEMM: 64x128x128; wave h covers out cols [h*32, h*32+32)
    f32x4 pacc[4][2] = {};
    #pragma unroll
    for (int s = 0; s < 4; s++){
        bf16x8 pa[4], pbk[2];
        #pragma unroll
        for (int i = 0; i < 4; i++)
            pa[i] = *(const bf16x8*)&Osm[(i*16 + m)*OSTR + s*32 + quad*8];
        #pragma unroll
        for (int j = 0; j < 2; j++)
            pbk[j] = *(const bf16x8*)&pw[(size_t)(h*Dh + j*16 + m)*Cdim
                                         + s*32 + quad*8];
        #pragma unroll
        for (int i = 0; i < 4; i++)
            #pragma unroll
            for (int j = 0; j < 2; j++)
                pacc[i][j] = __builtin_amdgcn_mfma_f32_16x16x32_bf16(
                                 pa[i], pbk[j], pacc[i][j], 0, 0, 0);
    }
    __syncthreads();   // all Osm reads done

    // stage proj result (+bias) back into Osm
    #pragma unroll
    for (int i = 0; i < 4; i++)
        #pragma unroll
        for (int j = 0; j < 2; j++){
            int c = h*Dh + j*16 + m;
            float bia = pb[c];
            #pragma unroll
            for (int rg = 0; rg < 4; rg++)
                Osm[(i*16 + quad*4 + rg)*OSTR + c] = f2bf(pacc[i][j][rg] + bia);
        }
    __syncthreads();

    // coalesced store: 64 rows x 128 u16 = 1024 chunks of 16 B
    #pragma unroll
    for (int it = 0; it < 4; it++){
        int idx = it*256 + t;
        int r = idx >> 4, c16 = idx & 15;
        *(bf16x8*)&projout[((size_t)w*64 + r)*Cdim + c16*8] =
            *(const bf16x8*)&Osm[r*OSTR + c16*8];
    }
}

extern "C" void kernel_launch(void* const* d_in, const int* in_sizes, int n_in,
                              void* d_out, int out_size, void* d_ws, size_t ws_size,
                              hipStream_t stream) {
    const float* x     = (const float*)d_in[0];
    const float* rpb   = (const float*)d_in[1];
    const float* n1g   = (const float*)d_in[2];
    const float* n1b   = (const float*)d_in[3];
    const float* qkvw  = (const float*)d_in[4];
    const float* qkvb  = (const float*)d_in[5];
    const float* projw = (const float*)d_in[6];
    const float* projb = (const float*)d_in[7];
    const float* n2g   = (const float*)d_in[8];
    const float* n2b   = (const float*)d_in[9];
    const float* fc1w  = (const float*)d_in[10];
    const float* fc1b  = (const float*)d_in[11];
    const float* fc2w  = (const float*)d_in[12];
    const float* fc2b  = (const float*)d_in[13];
    float* out = (float*)d_out;

    if (ws_size < (size_t)230u * 1024u * 1024u) return;

    // Disjoint-lifetime layout (race-free):
    //   region        offset   size   lifetime
    //   projout       0        32M    s2 -> s3
    //   qbuf          32M      32M    s1 -> s2
    //   kbuf          64M      32M    s1 -> s2
    //   vbuf          96M      32M    s1 -> s2
    //   weights/bmt   224M     ~2M    s0 -> end
    char* ws = (char*)d_ws;
    u16*  projout = (u16*)(ws);
    u16*  qbuf    = (u16*)(ws + ((size_t)32  << 20));
    u16*  kbuf    = (u16*)(ws + ((size_t)64  << 20));
    u16*  vbuf    = (u16*)(ws + ((size_t)96  << 20));
    u16*  wb      = (u16*)(ws + ((size_t)224 << 20));
    u16*  qkvw_b  = wb;                // 49152
    u16*  projw_b = wb + 49152;        // 16384
    u16*  fc1w_b  = wb + 65536;        // 65536
    u16*  fc2w_b  = wb + 131072;       // 65536
    float* bmt    = (float*)(ws + ((size_t)225 << 20)); // 256 KiB

    // 0. weight conversions + bias/mask table
    cvt_kernel<<<(49152+255)/256, 256, 0, stream>>>(qkvw, qkvw_b, 49152);
    cvt_kernel<<<(16384+255)/256, 256, 0, stream>>>(projw, projw_b, 16384);
    cvt_kernel<<<(65536+255)/256, 256, 0, stream>>>(fc1w, fc1w_b, 65536);
    cvt_kernel<<<(65536+255)/256, 256, 0, stream>>>(fc2w, fc2w_b, 65536);
    bm_kernel<<<256, 256, 0, stream>>>(rpb, bmt);

    // 1. fused LN1 + QKV GEMM (q/k per-head, v transposed)
    ln1qkv_kernel<<<dim3(3, Mrows/128), 256, 0, stream>>>(
        x, n1g, n1b, qkvw_b, qkvb, qbuf, kbuf, vbuf);
    // 2. fused MFMA windowed attention + proj (block = window)
    attnproj_kernel<<<WTOT, 256, 0, stream>>>(qbuf, kbuf, vbuf, bmt,
                                              projw_b, projb, projout);
    // 3. fused residual + LN2 + MLP -> out (64-row tiles, 4 blocks/CU)
    mlp_kernel<<<Mrows/64, 256, 0, stream>>>(
        x, projout, n2g, n2b, fc1w_b, fc1b, fc2w_b, fc2b, out);
}

// Round 7
// 395.393 us; speedup vs baseline: 1.1793x; 1.1793x over previous
//
#include <hip/hip_runtime.h>
#include <math.h>

typedef unsigned short u16;
typedef unsigned int   u32;

#define SS_    4
#define NH     4
#define Dh     32
#define Cdim   128
#define Ntok   64
#define WTOT   2048
#define Mrows  131072   // WTOT * Ntok
#define HIDDEN 512
#define PSTR   72       // attn P LDS row stride (u16)
#define OSTR   136      // attn Osm row stride (u16): 272 B, 16-B aligned
#define HPAD   136      // LDS row stride (u16): 272 B, 16-B aligned

typedef __bf16 bf16x8 __attribute__((ext_vector_type(8)));
typedef u16    u16x8  __attribute__((ext_vector_type(8)));
typedef float  f32x4  __attribute__((ext_vector_type(4)));

__device__ __forceinline__ float bf2f(u16 u){
    union {u32 i; float f;} v; v.i = ((u32)u) << 16; return v.f;
}
__device__ __forceinline__ u16 f2bf(float f){
    union {float f; u32 i;} v; v.f = f;
    u32 x = v.i;
    return (u16)((x + 0x7fffu + ((x >> 16) & 1u)) >> 16);
}

// GELU with A&S 7.1.26 erf approx (max err 1.5e-7)
__device__ __forceinline__ float fast_gelu(float v){
    float a = v * 0.70710678118654752f;
    float x = fabsf(a);
    float t = 1.0f / (1.0f + 0.3275911f * x);
    float p = ((((1.061405429f*t - 1.453152027f)*t + 1.421413741f)*t
                - 0.284496736f)*t + 0.254829592f)*t;
    float e = __expf(-x*x);
    float er = copysignf(1.0f - p*e, a);
    return 0.5f * v * (1.0f + er);
}

// token (windowed row) -> original token index (bijection, shift +4 both dims)
__device__ __forceinline__ int map_row_to_token(int r){
    int w = r >> 6, n = r & 63;
    int b = w >> 8, win = w & 255;
    int wy = win >> 4, wx = win & 15;
    int iy = n >> 3, ix = n & 7;
    int ro = (wy*8 + iy + SS_) & 127;
    int co = (wx*8 + ix + SS_) & 127;
    return (b << 14) + (ro << 7) + co;
}

// token index -> windowed row (inverse map)
__device__ __forceinline__ int map_token_to_row(int t){
    int b = t >> 14, ro = (t >> 7) & 127, co = t & 127;
    int y  = (ro + 128 - SS_) & 127;
    int xq = (co + 128 - SS_) & 127;
    return (((b << 8) | ((y >> 3) << 4) | (xq >> 3)) << 6) + (y & 7)*8 + (xq & 7);
}

// ---------------- fp32 -> bf16 weight conversion ----------------
__global__ void __launch_bounds__(256) cvt_kernel(const float* __restrict__ src,
        u16* __restrict__ dst, int n)
{
    int i = blockIdx.x * 256 + threadIdx.x;
    if (i < n) dst[i] = f2bf(src[i]);
}

// ---------------- bias+mask table: bm[cls][h][row][col], 4*4*64*64 fp32 ----------
__global__ void __launch_bounds__(256) bm_kernel(const float* __restrict__ rpb,
        float* __restrict__ bmt)
{
    int e = blockIdx.x * 256 + threadIdx.x;     // 65536 total
    int cls = e >> 14, h = (e >> 12) & 3, row = (e >> 6) & 63, col = e & 63;
    int iy = row >> 3, ix = row & 7, jy = col >> 3, jx = col & 7;
    int bidx = (iy - jy + 7)*15 + (ix - jx + 7);
    float bias = rpb[bidx*NH + h];
    int ybit = cls >> 1, xbit = cls & 1;
    int ri = (ybit ? (iy < 4 ? 1 : 2) : 0)*3 + (xbit ? (ix < 4 ? 1 : 2) : 0);
    int rj = (ybit ? (jy < 4 ? 1 : 2) : 0)*3 + (xbit ? (jx < 4 ? 1 : 2) : 0);
    bmt[e] = bias + ((ri != rj) ? -100.0f : 0.0f);
}

// ---- Fused LN1 + QKV GEMM. 1-D grid 3072 with XCD-aware decode: the three
// which-blocks of tile t get IDs {g*24 + which*8 + (t&7)} -> same (id % 8)
// -> same XCD -> the LN1'd x-tile is HBM-fetched once per tile, not 3x.
__global__ void __launch_bounds__(256, 4) ln1qkv_kernel(
        const float* __restrict__ x,
        const float* __restrict__ g, const float* __restrict__ bsh,
        const u16* __restrict__ Bw,      // qkvw_b [384][128]
        const float* __restrict__ bias,  // qkvb [384]
        u16* __restrict__ qb, u16* __restrict__ kb, u16* __restrict__ vb)
{
    __shared__ __align__(16) u16 Asm[128*HPAD];   // 34816 B
    int t = threadIdx.x;
    int u = blockIdx.x;                           // 0..3071
    int grp = u / 24, r24 = u % 24;
    int which = r24 >> 3;                         // 0=q 1=k 2=v
    int tl = (grp << 3) | (r24 & 7);              // tile 0..1023
    size_t tilebase = (size_t)tl * 128;

    // stage: LN1 over each windowed row (16-lane group owns one row)
    #pragma unroll
    for (int it = 0; it < 8; it++){
        int idx = it*256 + t;
        int rr  = idx >> 4, c8 = idx & 15;
        int trow = (int)tilebase + rr;
        int src  = map_row_to_token(trow);
        f32x4 xa = *(const f32x4*)&x[(size_t)src*Cdim + c8*8];
        f32x4 xb = *(const f32x4*)&x[(size_t)src*Cdim + c8*8 + 4];
        float s = 0.0f, s2 = 0.0f;
        #pragma unroll
        for (int k = 0; k < 4; k++){
            s += xa[k] + xb[k];
            s2 += xa[k]*xa[k] + xb[k]*xb[k];
        }
        #pragma unroll
        for (int off = 1; off <= 8; off <<= 1){
            s  += __shfl_xor(s,  off, 64);
            s2 += __shfl_xor(s2, off, 64);
        }
        float mean = s * (1.0f/128.0f);
        float var  = s2 * (1.0f/128.0f) - mean*mean;
        float inv  = rsqrtf(var + 1e-5f);
        f32x4 ga = *(const f32x4*)&g[c8*8],  gb = *(const f32x4*)&g[c8*8 + 4];
        f32x4 ba = *(const f32x4*)&bsh[c8*8], bb = *(const f32x4*)&bsh[c8*8 + 4];
        u16x8 ov;
        #pragma unroll
        for (int k = 0; k < 4; k++){
            ov[k]   = f2bf((xa[k] - mean) * inv * ga[k] + ba[k]);
            ov[k+4] = f2bf((xb[k] - mean) * inv * gb[k] + bb[k]);
        }
        *(u16x8*)&Asm[rr*HPAD + c8*8] = ov;
    }
    __syncthreads();

    int wave = t >> 6, lane = t & 63;
    int wr = wave & 1, wc = wave >> 1;
    int m = lane & 15, quad = lane >> 4;

    f32x4 acc[4][4] = {};
    #pragma unroll
    for (int s = 0; s < 4; s++){
        bf16x8 aq[4], bk[4];
        #pragma unroll
        for (int i = 0; i < 4; i++)
            aq[i] = *(const bf16x8*)&Asm[(wr*64 + i*16 + m)*HPAD + s*32 + quad*8];
        #pragma unroll
        for (int j = 0; j < 4; j++)
            bk[j] = *(const bf16x8*)&Bw[(size_t)(which*128 + wc*64 + j*16 + m)*Cdim
                                        + s*32 + quad*8];
        #pragma unroll
        for (int i = 0; i < 4; i++)
            #pragma unroll
            for (int j = 0; j < 4; j++)
                acc[i][j] = __builtin_amdgcn_mfma_f32_16x16x32_bf16(
                                aq[i], bk[j], acc[i][j], 0, 0, 0);
    }

    // qkv scatter epilogue (q scaled, k normal, v transposed [w][h][d][n])
    #pragma unroll
    for (int i = 0; i < 4; i++){
        #pragma unroll
        for (int j = 0; j < 4; j++){
            int c = which*128 + wc*64 + j*16 + m;
            float bia = bias[c];
            int h = (c >> 5) & 3;
            int d = c & 31;
            #pragma unroll
            for (int rg = 0; rg < 4; rg++){
                int r = (int)tilebase + wr*64 + i*16 + quad*4 + rg;
                float v = acc[i][j][rg] + bia;
                int w = r >> 6, n = r & 63;
                if (which == 0){
                    qb[((size_t)(w*NH + h)*Ntok + n)*Dh + d] =
                        f2bf(v * 0.17677669529663687f);
                } else if (which == 1){
                    kb[((size_t)(w*NH + h)*Ntok + n)*Dh + d] = f2bf(v);
                } else {
                    vb[((size_t)(w*NH + h)*Dh + d)*Ntok + n] = f2bf(v);
                }
            }
        }
    }
}

// --- Fused residual + LN2 + MLP (proven round-5 config: 128-row tiles,
// 2 blocks/CU, weights stay L2-resident):
//   out = (x + proj~) + GELU(LN2(x + proj~) @ W1^T + b1) @ W2^T + b2
__global__ void __launch_bounds__(256, 2) mlp_kernel(
        const float* __restrict__ x,     // [Mrows][128] fp32, token order
        const u16* __restrict__ projout, // [Mrows][128] bf16, windowed order
        const float* __restrict__ g, const float* __restrict__ bsh,
        const u16* __restrict__ W1,      // fc1w [512][128] bf16
        const float* __restrict__ b1,
        const u16* __restrict__ W2,      // fc2w [128][512] bf16
        const float* __restrict__ b2,
        float* __restrict__ outp)        // out  [Mrows][128] fp32
{
    __shared__ __align__(16) u16 Asm[128*HPAD];
    __shared__ __align__(16) u16 Hsm[128*HPAD];
    int t = threadIdx.x;
    int wave = t >> 6, lane = t & 63;
    int wr = wave & 1, wc = wave >> 1;
    int m = lane & 15, quad = lane >> 4;
    size_t rowbase = (size_t)blockIdx.x * 128;

    // ---- fused stage: val = x + proj~, LN2 -> bf16 Asm tile ----
    #pragma unroll
    for (int it = 0; it < 8; it++){
        int idx  = it*256 + t;
        int r    = idx >> 4, c8 = idx & 15;
        int trow = (int)rowbase + r;
        int rr   = map_token_to_row(trow);
        f32x4 xa = *(const f32x4*)&x[(size_t)trow*Cdim + c8*8];
        f32x4 xb = *(const f32x4*)&x[(size_t)trow*Cdim + c8*8 + 4];
        u16x8 pv = *(const u16x8*)&projout[(size_t)rr*Cdim + c8*8];
        float val[8];
        float s = 0.0f, s2 = 0.0f;
        #pragma unroll
        for (int k = 0; k < 8; k++){
            float xv = (k < 4) ? xa[k] : xb[k-4];
            val[k] = xv + bf2f(pv[k]);
            s += val[k]; s2 += val[k]*val[k];
        }
        #pragma unroll
        for (int off = 1; off <= 8; off <<= 1){
            s  += __shfl_xor(s,  off, 64);
            s2 += __shfl_xor(s2, off, 64);
        }
        float mean = s * (1.0f/128.0f);
        float var  = s2 * (1.0f/128.0f) - mean*mean;
        float inv  = rsqrtf(var + 1e-5f);
        f32x4 ga = *(const f32x4*)&g[c8*8],  gb = *(const f32x4*)&g[c8*8 + 4];
        f32x4 ba = *(const f32x4*)&bsh[c8*8], bb = *(const f32x4*)&bsh[c8*8 + 4];
        u16x8 ov;
        #pragma unroll
        for (int k = 0; k < 8; k++){
            float gv = (k < 4) ? ga[k] : gb[k-4];
            float bv = (k < 4) ? ba[k] : bb[k-4];
            ov[k] = f2bf((val[k] - mean) * inv * gv + bv);
        }
        *(u16x8*)&Asm[r*HPAD + c8*8] = ov;
    }
    __syncthreads();

    f32x4 O[4][4] = {};                  // persistent 64x64 out tile per wave

    for (int kk = 0; kk < 4; kk++){
        // ---- H chunk: Hc = GELU(A @ W1[kk*128 ..][:]^T + b1) ----
        f32x4 Hacc[4][4] = {};
        #pragma unroll
        for (int s = 0; s < 4; s++){
            bf16x8 aq[4], bk[4];
            #pragma unroll
            for (int i = 0; i < 4; i++)
                aq[i] = *(const bf16x8*)&Asm[(wr*64 + i*16 + m)*HPAD + s*32 + quad*8];
            #pragma unroll
            for (int j = 0; j < 4; j++)
                bk[j] = *(const bf16x8*)&W1[(size_t)(kk*128 + wc*64 + j*16 + m)*Cdim
                                            + s*32 + quad*8];
            #pragma unroll
            for (int i = 0; i < 4; i++)
                #pragma unroll
                for (int j = 0; j < 4; j++)
                    Hacc[i][j] = __builtin_amdgcn_mfma_f32_16x16x32_bf16(
                                     aq[i], bk[j], Hacc[i][j], 0, 0, 0);
        }
        #pragma unroll
        for (int i = 0; i < 4; i++){
            #pragma unroll
            for (int j = 0; j < 4; j++){
                int hc = wc*64 + j*16 + m;          // hidden col within chunk
                float bia = b1[kk*128 + hc];
                #pragma unroll
                for (int rg = 0; rg < 4; rg++){
                    int r = wr*64 + i*16 + quad*4 + rg;
                    Hsm[r*HPAD + hc] = f2bf(fast_gelu(Hacc[i][j][rg] + bia));
                }
            }
        }
        __syncthreads();

        // ---- O += Hc @ W2[:, kk*128 ..]^T ----
        #pragma unroll
        for (int s = 0; s < 4; s++){
            bf16x8 pa[4], bk[4];
            #pragma unroll
            for (int i = 0; i < 4; i++)
                pa[i] = *(const bf16x8*)&Hsm[(wr*64 + i*16 + m)*HPAD + s*32 + quad*8];
            #pragma unroll
            for (int j = 0; j < 4; j++)
                bk[j] = *(const bf16x8*)&W2[(size_t)(wc*64 + j*16 + m)*HIDDEN
                                            + kk*128 + s*32 + quad*8];
            #pragma unroll
            for (int i = 0; i < 4; i++)
                #pragma unroll
                for (int j = 0; j < 4; j++)
                    O[i][j] = __builtin_amdgcn_mfma_f32_16x16x32_bf16(
                                  pa[i], bk[j], O[i][j], 0, 0, 0);
        }
        __syncthreads();   // Hsm reused next chunk
    }

    // ---- epilogue: out = (x + proj~) + O + b2 (x/proj re-read; L2-hot) ----
    #pragma unroll
    for (int i = 0; i < 4; i++){
        #pragma unroll
        for (int rg = 0; rg < 4; rg++){
            int r  = (int)rowbase + wr*64 + i*16 + quad*4 + rg;   // token row
            int rr = map_token_to_row(r);
            #pragma unroll
            for (int j = 0; j < 4; j++){
                int c = wc*64 + j*16 + m;
                float v = x[(size_t)r*Cdim + c] + bf2f(projout[(size_t)rr*Cdim + c])
                          + O[i][j][rg] + b2[c];
                outp[(size_t)r*Cdim + c] = v;
            }
        }
    }
}

// ------- Fused attention + proj: block = window, wave = head -------------------
__global__ void __launch_bounds__(256) attnproj_kernel(
        const u16* __restrict__ qb, const u16* __restrict__ kb,
        const u16* __restrict__ vt, const float* __restrict__ bmt,
        const u16* __restrict__ pw, const float* __restrict__ pb,
        u16* __restrict__ projout)
{
    __shared__ __align__(16) u16 SH[NH*64*PSTR];   // 36864 B; P + (union) Osm
    int w = blockIdx.x;
    int win = w & 255;
    int wy = win >> 4, wx = win & 15;
    int cls = ((wy == 15) ? 2 : 0) | ((wx == 15) ? 1 : 0);
    int t = threadIdx.x;
    int h = t >> 6, lane = t & 63;
    int m = lane & 15, quad = lane >> 4;
    u16* Ph  = SH + h*64*PSTR;     // per-wave private P rows
    u16* Osm = SH;                 // 64 x OSTR union view (after barrier 1)

    const u16* qg = qb + (size_t)(w*NH + h)*2048;   // [n][d]
    const u16* kg = kb + (size_t)(w*NH + h)*2048;   // [n][d]
    const u16* vg = vt + (size_t)(w*NH + h)*2048;   // [d][n] (transposed)
    const float* bm = bmt + (size_t)(cls*NH + h)*4096;

    // S = Q @ K^T  (64x64, one K=32 step)
    bf16x8 aq[4], bk[4];
    #pragma unroll
    for (int i = 0; i < 4; i++)
        aq[i] = *(const bf16x8*)&qg[(i*16 + m)*32 + quad*8];
    #pragma unroll
    for (int j = 0; j < 4; j++)
        bk[j] = *(const bf16x8*)&kg[(j*16 + m)*32 + quad*8];
    f32x4 S[4][4] = {};
    #pragma unroll
    for (int i = 0; i < 4; i++)
        #pragma unroll
        for (int j = 0; j < 4; j++)
            S[i][j] = __builtin_amdgcn_mfma_f32_16x16x32_bf16(
                          aq[i], bk[j], S[i][j], 0, 0, 0);

    // bias+mask add, row softmax -> P (bf16, per-wave private; no barrier)
    #pragma unroll
    for (int i = 0; i < 4; i++){
        #pragma unroll
        for (int rg = 0; rg < 4; rg++){
            int row = i*16 + quad*4 + rg;
            float s0 = S[i][0][rg] + bm[row*64 +  0 + m];
            float s1 = S[i][1][rg] + bm[row*64 + 16 + m];
            float s2 = S[i][2][rg] + bm[row*64 + 32 + m];
            float s3 = S[i][3][rg] + bm[row*64 + 48 + m];
            float mx = fmaxf(fmaxf(s0, s1), fmaxf(s2, s3));
            mx = fmaxf(mx, __shfl_xor(mx, 1, 64));
            mx = fmaxf(mx, __shfl_xor(mx, 2, 64));
            mx = fmaxf(mx, __shfl_xor(mx, 4, 64));
            mx = fmaxf(mx, __shfl_xor(mx, 8, 64));
            s0 = __expf(s0 - mx); s1 = __expf(s1 - mx);
            s2 = __expf(s2 - mx); s3 = __expf(s3 - mx);
            float sm = s0 + s1 + s2 + s3;
            sm += __shfl_xor(sm, 1, 64);
            sm += __shfl_xor(sm, 2, 64);
            sm += __shfl_xor(sm, 4, 64);
            sm += __shfl_xor(sm, 8, 64);
            float rinv = 1.0f / sm;
            u16* pr = &Ph[row*PSTR];
            pr[ 0 + m] = f2bf(s0 * rinv);
            pr[16 + m] = f2bf(s1 * rinv);
            pr[32 + m] = f2bf(s2 * rinv);
            pr[48 + m] = f2bf(s3 * rinv);
        }
    }

    // O = P @ V  (64x32, two K=32 steps)
    f32x4 O[4][2] = {};
    #pragma unroll
    for (int s2 = 0; s2 < 2; s2++){
        bf16x8 pa[4], bv[2];
        #pragma unroll
        for (int i = 0; i < 4; i++)
            pa[i] = *(const bf16x8*)&Ph[(i*16 + m)*PSTR + s2*32 + quad*8];
        #pragma unroll
        for (int dt = 0; dt < 2; dt++)
            bv[dt] = *(const bf16x8*)&vg[(dt*16 + m)*64 + s2*32 + quad*8];
        #pragma unroll
        for (int i = 0; i < 4; i++)
            #pragma unroll
            for (int dt = 0; dt < 2; dt++)
                O[i][dt] = __builtin_amdgcn_mfma_f32_16x16x32_bf16(
                               pa[i], bv[dt], O[i][dt], 0, 0, 0);
    }

    __syncthreads();   // all P reads done; SH is reused as Osm below

    // stage head-concat tile: Osm[row][h*32 + dt*16 + m]
    #pragma unroll
    for (int i = 0; i < 4; i++)
        #pragma unroll
        for (int dt = 0; dt < 2; dt++)
            #pragma unroll
            for (int rg = 0; rg < 4; rg++)
                Osm[(i*16 + quad*4 + rg)*OSTR + h*Dh + dt*16 + m] =
                    f2bf(O[i][dt][rg]);
    __syncthreads();

    // proj GEMM: 64x128x128; wave h covers out cols [h*32, h*32+32)
    f32x4 pacc[4][2] = {};
    #pragma unroll
    for (int s = 0; s < 4; s++){
        bf16x8 pa[4], pbk[2];
        #pragma unroll
        for (int i = 0; i < 4; i++)
            pa[i] = *(const bf16x8*)&Osm[(i*16 + m)*OSTR + s*32 + quad*8];
        #pragma unroll
        for (int j = 0; j < 2; j++)
            pbk[j] = *(const bf16x8*)&pw[(size_t)(h*Dh + j*16 + m)*Cdim
                                         + s*32 + quad*8];
        #pragma unroll
        for (int i = 0; i < 4; i++)
            #pragma unroll
            for (int j = 0; j < 2; j++)
                pacc[i][j] = __builtin_amdgcn_mfma_f32_16x16x32_bf16(
                                 pa[i], pbk[j], pacc[i][j], 0, 0, 0);
    }
    __syncthreads();   // all Osm reads done

    // stage proj result (+bias) back into Osm
    #pragma unroll
    for (int i = 0; i < 4; i++)
        #pragma unroll
        for (int j = 0; j < 2; j++){
            int c = h*Dh + j*16 + m;
            float bia = pb[c];
            #pragma unroll
            for (int rg = 0; rg < 4; rg++)
                Osm[(i*16 + quad*4 + rg)*OSTR + c] = f2bf(pacc[i][j][rg] + bia);
        }
    __syncthreads();

    // coalesced store: 64 rows x 128 u16 = 1024 chunks of 16 B
    #pragma unroll
    for (int it = 0; it < 4; it++){
        int idx = it*256 + t;
        int r = idx >> 4, c16 = idx & 15;
        *(bf16x8*)&projout[((size_t)w*64 + r)*Cdim + c16*8] =
            *(const bf16x8*)&Osm[r*OSTR + c16*8];
    }
}

extern "C" void kernel_launch(void* const* d_in, const int* in_sizes, int n_in,
                              void* d_out, int out_size, void* d_ws, size_t ws_size,
                              hipStream_t stream) {
    const float* x     = (const float*)d_in[0];
    const float* rpb   = (const float*)d_in[1];
    const float* n1g   = (const float*)d_in[2];
    const float* n1b   = (const float*)d_in[3];
    const float* qkvw  = (const float*)d_in[4];
    const float* qkvb  = (const float*)d_in[5];
    const float* projw = (const float*)d_in[6];
    const float* projb = (const float*)d_in[7];
    const float* n2g   = (const float*)d_in[8];
    const float* n2b   = (const float*)d_in[9];
    const float* fc1w  = (const float*)d_in[10];
    const float* fc1b  = (const float*)d_in[11];
    const float* fc2w  = (const float*)d_in[12];
    const float* fc2b  = (const float*)d_in[13];
    float* out = (float*)d_out;

    if (ws_size < (size_t)230u * 1024u * 1024u) return;

    // Disjoint-lifetime layout (race-free):
    //   region        offset   size   lifetime
    //   projout       0        32M    s2 -> s3
    //   qbuf          32M      32M    s1 -> s2
    //   kbuf          64M      32M    s1 -> s2
    //   vbuf          96M      32M    s1 -> s2
    //   weights/bmt   224M     ~2M    s0 -> end
    char* ws = (char*)d_ws;
    u16*  projout = (u16*)(ws);
    u16*  qbuf    = (u16*)(ws + ((size_t)32  << 20));
    u16*  kbuf    = (u16*)(ws + ((size_t)64  << 20));
    u16*  vbuf    = (u16*)(ws + ((size_t)96  << 20));
    u16*  wb      = (u16*)(ws + ((size_t)224 << 20));
    u16*  qkvw_b  = wb;                // 49152
    u16*  projw_b = wb + 49152;        // 16384
    u16*  fc1w_b  = wb + 65536;        // 65536
    u16*  fc2w_b  = wb + 131072;       // 65536
    float* bmt    = (float*)(ws + ((size_t)225 << 20)); // 256 KiB

    // 0. weight conversions + bias/mask table
    cvt_kernel<<<(49152+255)/256, 256, 0, stream>>>(qkvw, qkvw_b, 49152);
    cvt_kernel<<<(16384+255)/256, 256, 0, stream>>>(projw, projw_b, 16384);
    cvt_kernel<<<(65536+255)/256, 256, 0, stream>>>(fc1w, fc1w_b, 65536);
    cvt_kernel<<<(65536+255)/256, 256, 0, stream>>>(fc2w, fc2w_b, 65536);
    bm_kernel<<<256, 256, 0, stream>>>(rpb, bmt);

    // 1. fused LN1 + QKV GEMM (XCD-aware 1-D grid: 3 which-blocks/tile on same XCD)
    ln1qkv_kernel<<<3072, 256, 0, stream>>>(
        x, n1g, n1b, qkvw_b, qkvb, qbuf, kbuf, vbuf);
    // 2. fused MFMA windowed attention + proj (block = window)
    attnproj_kernel<<<WTOT, 256, 0, stream>>>(qbuf, kbuf, vbuf, bmt,
                                              projw_b, projb, projout);
    // 3. fused residual + LN2 + MLP -> out (128-row tiles, 2 blocks/CU)
    mlp_kernel<<<Mrows/128, 256, 0, stream>>>(
        x, projout, n2g, n2b, fc1w_b, fc1b, fc2w_b, fc2b, out);
}

// Round 8
// 372.770 us; speedup vs baseline: 1.2509x; 1.0607x over previous
//
#include <hip/hip_runtime.h>
#include <math.h>

typedef unsigned short u16;
typedef unsigned int   u32;

#define SS_    4
#define NH     4
#define Dh     32
#define Cdim   128
#define Ntok   64
#define WTOT   2048
#define Mrows  131072   // WTOT * Ntok
#define HIDDEN 512
#define PSTR   72       // attn P LDS row stride (u16)
#define OSTR   136      // attn Osm row stride (u16): 272 B, 16-B aligned
#define HPAD   136      // LDS row stride (u16): 272 B, 16-B aligned

typedef __bf16 bf16x8 __attribute__((ext_vector_type(8)));
typedef u16    u16x8  __attribute__((ext_vector_type(8)));
typedef float  f32x4  __attribute__((ext_vector_type(4)));

__device__ __forceinline__ float bf2f(u16 u){
    union {u32 i; float f;} v; v.i = ((u32)u) << 16; return v.f;
}
__device__ __forceinline__ u16 f2bf(float f){
    union {float f; u32 i;} v; v.f = f;
    u32 x = v.i;
    return (u16)((x + 0x7fffu + ((x >> 16) & 1u)) >> 16);
}

// GELU with A&S 7.1.26 erf approx (max err 1.5e-7)
__device__ __forceinline__ float fast_gelu(float v){
    float a = v * 0.70710678118654752f;
    float x = fabsf(a);
    float t = 1.0f / (1.0f + 0.3275911f * x);
    float p = ((((1.061405429f*t - 1.453152027f)*t + 1.421413741f)*t
                - 0.284496736f)*t + 0.254829592f)*t;
    float e = __expf(-x*x);
    float er = copysignf(1.0f - p*e, a);
    return 0.5f * v * (1.0f + er);
}

// token (windowed row) -> original token index (bijection, shift +4 both dims)
__device__ __forceinline__ int map_row_to_token(int r){
    int w = r >> 6, n = r & 63;
    int b = w >> 8, win = w & 255;
    int wy = win >> 4, wx = win & 15;
    int iy = n >> 3, ix = n & 7;
    int ro = (wy*8 + iy + SS_) & 127;
    int co = (wx*8 + ix + SS_) & 127;
    return (b << 14) + (ro << 7) + co;
}

// token index -> windowed row (inverse map)
__device__ __forceinline__ int map_token_to_row(int t){
    int b = t >> 14, ro = (t >> 7) & 127, co = t & 127;
    int y  = (ro + 128 - SS_) & 127;
    int xq = (co + 128 - SS_) & 127;
    return (((b << 8) | ((y >> 3) << 4) | (xq >> 3)) << 6) + (y & 7)*8 + (xq & 7);
}

// ---------------- fp32 -> bf16 weight conversion ----------------
__global__ void __launch_bounds__(256) cvt_kernel(const float* __restrict__ src,
        u16* __restrict__ dst, int n)
{
    int i = blockIdx.x * 256 + threadIdx.x;
    if (i < n) dst[i] = f2bf(src[i]);
}

// ---------------- bias+mask table: bm[cls][h][row][col], 4*4*64*64 fp32 ----------
__global__ void __launch_bounds__(256) bm_kernel(const float* __restrict__ rpb,
        float* __restrict__ bmt)
{
    int e = blockIdx.x * 256 + threadIdx.x;     // 65536 total
    int cls = e >> 14, h = (e >> 12) & 3, row = (e >> 6) & 63, col = e & 63;
    int iy = row >> 3, ix = row & 7, jy = col >> 3, jx = col & 7;
    int bidx = (iy - jy + 7)*15 + (ix - jx + 7);
    float bias = rpb[bidx*NH + h];
    int ybit = cls >> 1, xbit = cls & 1;
    int ri = (ybit ? (iy < 4 ? 1 : 2) : 0)*3 + (xbit ? (ix < 4 ? 1 : 2) : 0);
    int rj = (ybit ? (jy < 4 ? 1 : 2) : 0)*3 + (xbit ? (jx < 4 ? 1 : 2) : 0);
    bmt[e] = bias + ((ri != rj) ? -100.0f : 0.0f);
}

// ---- Fused LN1 + QKV GEMM. 1-D grid 3072 with XCD-aware decode: the three
// which-blocks of tile t get IDs {g*24 + which*8 + (t&7)} -> same (id % 8)
// -> same XCD -> the LN1'd x-tile is HBM-fetched once per tile, not 3x.
__global__ void __launch_bounds__(256, 4) ln1qkv_kernel(
        const float* __restrict__ x,
        const float* __restrict__ g, const float* __restrict__ bsh,
        const u16* __restrict__ Bw,      // qkvw_b [384][128]
        const float* __restrict__ bias,  // qkvb [384]
        u16* __restrict__ qb, u16* __restrict__ kb, u16* __restrict__ vb)
{
    __shared__ __align__(16) u16 Asm[128*HPAD];   // 34816 B
    int t = threadIdx.x;
    int u = blockIdx.x;                           // 0..3071
    int grp = u / 24, r24 = u % 24;
    int which = r24 >> 3;                         // 0=q 1=k 2=v
    int tl = (grp << 3) | (r24 & 7);              // tile 0..1023
    size_t tilebase = (size_t)tl * 128;

    // stage: LN1 over each windowed row (16-lane group owns one row)
    #pragma unroll
    for (int it = 0; it < 8; it++){
        int idx = it*256 + t;
        int rr  = idx >> 4, c8 = idx & 15;
        int trow = (int)tilebase + rr;
        int src  = map_row_to_token(trow);
        f32x4 xa = *(const f32x4*)&x[(size_t)src*Cdim + c8*8];
        f32x4 xb = *(const f32x4*)&x[(size_t)src*Cdim + c8*8 + 4];
        float s = 0.0f, s2 = 0.0f;
        #pragma unroll
        for (int k = 0; k < 4; k++){
            s += xa[k] + xb[k];
            s2 += xa[k]*xa[k] + xb[k]*xb[k];
        }
        #pragma unroll
        for (int off = 1; off <= 8; off <<= 1){
            s  += __shfl_xor(s,  off, 64);
            s2 += __shfl_xor(s2, off, 64);
        }
        float mean = s * (1.0f/128.0f);
        float var  = s2 * (1.0f/128.0f) - mean*mean;
        float inv  = rsqrtf(var + 1e-5f);
        f32x4 ga = *(const f32x4*)&g[c8*8],  gb = *(const f32x4*)&g[c8*8 + 4];
        f32x4 ba = *(const f32x4*)&bsh[c8*8], bb = *(const f32x4*)&bsh[c8*8 + 4];
        u16x8 ov;
        #pragma unroll
        for (int k = 0; k < 4; k++){
            ov[k]   = f2bf((xa[k] - mean) * inv * ga[k] + ba[k]);
            ov[k+4] = f2bf((xb[k] - mean) * inv * gb[k] + bb[k]);
        }
        *(u16x8*)&Asm[rr*HPAD + c8*8] = ov;
    }
    __syncthreads();

    int wave = t >> 6, lane = t & 63;
    int wr = wave & 1, wc = wave >> 1;
    int m = lane & 15, quad = lane >> 4;

    f32x4 acc[4][4] = {};
    #pragma unroll
    for (int s = 0; s < 4; s++){
        bf16x8 aq[4], bk[4];
        #pragma unroll
        for (int i = 0; i < 4; i++)
            aq[i] = *(const bf16x8*)&Asm[(wr*64 + i*16 + m)*HPAD + s*32 + quad*8];
        #pragma unroll
        for (int j = 0; j < 4; j++)
            bk[j] = *(const bf16x8*)&Bw[(size_t)(which*128 + wc*64 + j*16 + m)*Cdim
                                        + s*32 + quad*8];
        #pragma unroll
        for (int i = 0; i < 4; i++)
            #pragma unroll
            for (int j = 0; j < 4; j++)
                acc[i][j] = __builtin_amdgcn_mfma_f32_16x16x32_bf16(
                                aq[i], bk[j], acc[i][j], 0, 0, 0);
    }

    // qkv scatter epilogue (q scaled, k normal, v transposed [w][h][d][n])
    #pragma unroll
    for (int i = 0; i < 4; i++){
        #pragma unroll
        for (int j = 0; j < 4; j++){
            int c = which*128 + wc*64 + j*16 + m;
            float bia = bias[c];
            int h = (c >> 5) & 3;
            int d = c & 31;
            #pragma unroll
            for (int rg = 0; rg < 4; rg++){
                int r = (int)tilebase + wr*64 + i*16 + quad*4 + rg;
                float v = acc[i][j][rg] + bia;
                int w = r >> 6, n = r & 63;
                if (which == 0){
                    qb[((size_t)(w*NH + h)*Ntok + n)*Dh + d] =
                        f2bf(v * 0.17677669529663687f);
                } else if (which == 1){
                    kb[((size_t)(w*NH + h)*Ntok + n)*Dh + d] = f2bf(v);
                } else {
                    vb[((size_t)(w*NH + h)*Dh + d)*Ntok + n] = f2bf(v);
                }
            }
        }
    }
}

// --- Fused residual + LN2 + MLP, 512-thread blocks (8 waves 2x4):
// LDS caps residency at 2 blocks/CU; bigger blocks -> 16 waves/CU (was 8),
// doubling latency hiding across the GEMM1->GELU->barrier->GEMM2 chain while
// keeping the proven 128-row tile + L2-resident weights (round-6 lesson).
__global__ void __launch_bounds__(512, 4) mlp_kernel(
        const float* __restrict__ x,     // [Mrows][128] fp32, token order
        const u16* __restrict__ projout, // [Mrows][128] bf16, windowed order
        const float* __restrict__ g, const float* __restrict__ bsh,
        const u16* __restrict__ W1,      // fc1w [512][128] bf16
        const float* __restrict__ b1,
        const u16* __restrict__ W2,      // fc2w [128][512] bf16
        const float* __restrict__ b2,
        float* __restrict__ outp)        // out  [Mrows][128] fp32
{
    __shared__ __align__(16) u16 Asm[128*HPAD];
    __shared__ __align__(16) u16 Hsm[128*HPAD];
    int t = threadIdx.x;
    int wave = t >> 6, lane = t & 63;
    int wr = wave & 1, wc = wave >> 1;           // wr: 0..1 (rows), wc: 0..3 (cols)
    int m = lane & 15, quad = lane >> 4;
    size_t rowbase = (size_t)blockIdx.x * 128;

    // ---- fused stage: val = x + proj~, LN2 -> bf16 Asm tile ----
    #pragma unroll
    for (int it = 0; it < 4; it++){
        int idx  = it*512 + t;
        int r    = idx >> 4, c8 = idx & 15;
        int trow = (int)rowbase + r;
        int rr   = map_token_to_row(trow);
        f32x4 xa = *(const f32x4*)&x[(size_t)trow*Cdim + c8*8];
        f32x4 xb = *(const f32x4*)&x[(size_t)trow*Cdim + c8*8 + 4];
        u16x8 pv = *(const u16x8*)&projout[(size_t)rr*Cdim + c8*8];
        float val[8];
        float s = 0.0f, s2 = 0.0f;
        #pragma unroll
        for (int k = 0; k < 8; k++){
            float xv = (k < 4) ? xa[k] : xb[k-4];
            val[k] = xv + bf2f(pv[k]);
            s += val[k]; s2 += val[k]*val[k];
        }
        #pragma unroll
        for (int off = 1; off <= 8; off <<= 1){
            s  += __shfl_xor(s,  off, 64);
            s2 += __shfl_xor(s2, off, 64);
        }
        float mean = s * (1.0f/128.0f);
        float var  = s2 * (1.0f/128.0f) - mean*mean;
        float inv  = rsqrtf(var + 1e-5f);
        f32x4 ga = *(const f32x4*)&g[c8*8],  gb = *(const f32x4*)&g[c8*8 + 4];
        f32x4 ba = *(const f32x4*)&bsh[c8*8], bb = *(const f32x4*)&bsh[c8*8 + 4];
        u16x8 ov;
        #pragma unroll
        for (int k = 0; k < 8; k++){
            float gv = (k < 4) ? ga[k] : gb[k-4];
            float bv = (k < 4) ? ba[k] : bb[k-4];
            ov[k] = f2bf((val[k] - mean) * inv * gv + bv);
        }
        *(u16x8*)&Asm[r*HPAD + c8*8] = ov;
    }
    __syncthreads();

    f32x4 O[4][2] = {};                  // 64 rows x 32 out cols per wave

    for (int kk = 0; kk < 4; kk++){
        // ---- H chunk: wave (wr,wc) computes rows wr*64..+64, hid cols wc*32..+32
        f32x4 Hacc[4][2] = {};
        #pragma unroll
        for (int s = 0; s < 4; s++){
            bf16x8 aq[4], bk[2];
            #pragma unroll
            for (int i = 0; i < 4; i++)
                aq[i] = *(const bf16x8*)&Asm[(wr*64 + i*16 + m)*HPAD + s*32 + quad*8];
            #pragma unroll
            for (int j = 0; j < 2; j++)
                bk[j] = *(const bf16x8*)&W1[(size_t)(kk*128 + wc*32 + j*16 + m)*Cdim
                                            + s*32 + quad*8];
            #pragma unroll
            for (int i = 0; i < 4; i++)
                #pragma unroll
                for (int j = 0; j < 2; j++)
                    Hacc[i][j] = __builtin_amdgcn_mfma_f32_16x16x32_bf16(
                                     aq[i], bk[j], Hacc[i][j], 0, 0, 0);
        }
        #pragma unroll
        for (int i = 0; i < 4; i++){
            #pragma unroll
            for (int j = 0; j < 2; j++){
                int hc = wc*32 + j*16 + m;          // hidden col within chunk
                float bia = b1[kk*128 + hc];
                #pragma unroll
                for (int rg = 0; rg < 4; rg++){
                    int r = wr*64 + i*16 + quad*4 + rg;
                    Hsm[r*HPAD + hc] = f2bf(fast_gelu(Hacc[i][j][rg] + bia));
                }
            }
        }
        __syncthreads();

        // ---- O += Hc @ W2[:, kk*128 ..]^T  (out cols wc*32..+32) ----
        #pragma unroll
        for (int s = 0; s < 4; s++){
            bf16x8 pa[4], bk[2];
            #pragma unroll
            for (int i = 0; i < 4; i++)
                pa[i] = *(const bf16x8*)&Hsm[(wr*64 + i*16 + m)*HPAD + s*32 + quad*8];
            #pragma unroll
            for (int j = 0; j < 2; j++)
                bk[j] = *(const bf16x8*)&W2[(size_t)(wc*32 + j*16 + m)*HIDDEN
                                            + kk*128 + s*32 + quad*8];
            #pragma unroll
            for (int i = 0; i < 4; i++)
                #pragma unroll
                for (int j = 0; j < 2; j++)
                    O[i][j] = __builtin_amdgcn_mfma_f32_16x16x32_bf16(
                                  pa[i], bk[j], O[i][j], 0, 0, 0);
        }
        __syncthreads();   // Hsm reused next chunk
    }

    // ---- epilogue: out = (x + proj~) + O + b2 (x/proj re-read; L2-hot) ----
    #pragma unroll
    for (int i = 0; i < 4; i++){
        #pragma unroll
        for (int rg = 0; rg < 4; rg++){
            int r  = (int)rowbase + wr*64 + i*16 + quad*4 + rg;   // token row
            int rr = map_token_to_row(r);
            #pragma unroll
            for (int j = 0; j < 2; j++){
                int c = wc*32 + j*16 + m;
                float v = x[(size_t)r*Cdim + c] + bf2f(projout[(size_t)rr*Cdim + c])
                          + O[i][j][rg] + b2[c];
                outp[(size_t)r*Cdim + c] = v;
            }
        }
    }
}

// ------- Fused attention + proj: block = window, wave = head -------------------
__global__ void __launch_bounds__(256) attnproj_kernel(
        const u16* __restrict__ qb, const u16* __restrict__ kb,
        const u16* __restrict__ vt, const float* __restrict__ bmt,
        const u16* __restrict__ pw, const float* __restrict__ pb,
        u16* __restrict__ projout)
{
    __shared__ __align__(16) u16 SH[NH*64*PSTR];   // 36864 B; P + (union) Osm
    int w = blockIdx.x;
    int win = w & 255;
    int wy = win >> 4, wx = win & 15;
    int cls = ((wy == 15) ? 2 : 0) | ((wx == 15) ? 1 : 0);
    int t = threadIdx.x;
    int h = t >> 6, lane = t & 63;
    int m = lane & 15, quad = lane >> 4;
    u16* Ph  = SH + h*64*PSTR;     // per-wave private P rows
    u16* Osm = SH;                 // 64 x OSTR union view (after barrier 1)

    const u16* qg = qb + (size_t)(w*NH + h)*2048;   // [n][d]
    const u16* kg = kb + (size_t)(w*NH + h)*2048;   // [n][d]
    const u16* vg = vt + (size_t)(w*NH + h)*2048;   // [d][n] (transposed)
    const float* bm = bmt + (size_t)(cls*NH + h)*4096;

    // S = Q @ K^T  (64x64, one K=32 step)
    bf16x8 aq[4], bk[4];
    #pragma unroll
    for (int i = 0; i < 4; i++)
        aq[i] = *(const bf16x8*)&qg[(i*16 + m)*32 + quad*8];
    #pragma unroll
    for (int j = 0; j < 4; j++)
        bk[j] = *(const bf16x8*)&kg[(j*16 + m)*32 + quad*8];
    f32x4 S[4][4] = {};
    #pragma unroll
    for (int i = 0; i < 4; i++)
        #pragma unroll
        for (int j = 0; j < 4; j++)
            S[i][j] = __builtin_amdgcn_mfma_f32_16x16x32_bf16(
                          aq[i], bk[j], S[i][j], 0, 0, 0);

    // bias+mask add, row softmax -> P (bf16, per-wave private; no barrier)
    #pragma unroll
    for (int i = 0; i < 4; i++){
        #pragma unroll
        for (int rg = 0; rg < 4; rg++){
            int row = i*16 + quad*4 + rg;
            float s0 = S[i][0][rg] + bm[row*64 +  0 + m];
            float s1 = S[i][1][rg] + bm[row*64 + 16 + m];
            float s2 = S[i][2][rg] + bm[row*64 + 32 + m];
            float s3 = S[i][3][rg] + bm[row*64 + 48 + m];
            float mx = fmaxf(fmaxf(s0, s1), fmaxf(s2, s3));
            mx = fmaxf(mx, __shfl_xor(mx, 1, 64));
            mx = fmaxf(mx, __shfl_xor(mx, 2, 64));
            mx = fmaxf(mx, __shfl_xor(mx, 4, 64));
            mx = fmaxf(mx, __shfl_xor(mx, 8, 64));
            s0 = __expf(s0 - mx); s1 = __expf(s1 - mx);
            s2 = __expf(s2 - mx); s3 = __expf(s3 - mx);
            float sm = s0 + s1 + s2 + s3;
            sm += __shfl_xor(sm, 1, 64);
            sm += __shfl_xor(sm, 2, 64);
            sm += __shfl_xor(sm, 4, 64);
            sm += __shfl_xor(sm, 8, 64);
            float rinv = 1.0f / sm;
            u16* pr = &Ph[row*PSTR];
            pr[ 0 + m] = f2bf(s0 * rinv);
            pr[16 + m] = f2bf(s1 * rinv);
            pr[32 + m] = f2bf(s2 * rinv);
            pr[48 + m] = f2bf(s3 * rinv);
        }
    }

    // O = P @ V  (64x32, two K=32 steps)
    f32x4 O[4][2] = {};
    #pragma unroll
    for (int s2 = 0; s2 < 2; s2++){
        bf16x8 pa[4], bv[2];
        #pragma unroll
        for (int i = 0; i < 4; i++)
            pa[i] = *(const bf16x8*)&Ph[(i*16 + m)*PSTR + s2*32 + quad*8];
        #pragma unroll
        for (int dt = 0; dt < 2; dt++)
            bv[dt] = *(const bf16x8*)&vg[(dt*16 + m)*64 + s2*32 + quad*8];
        #pragma unroll
        for (int i = 0; i < 4; i++)
            #pragma unroll
            for (int dt = 0; dt < 2; dt++)
                O[i][dt] = __builtin_amdgcn_mfma_f32_16x16x32_bf16(
                               pa[i], bv[dt], O[i][dt], 0, 0, 0);
    }

    __syncthreads();   // all P reads done; SH is reused as Osm below

    // stage head-concat tile: Osm[row][h*32 + dt*16 + m]
    #pragma unroll
    for (int i = 0; i < 4; i++)
        #pragma unroll
        for (int dt = 0; dt < 2; dt++)
            #pragma unroll
            for (int rg = 0; rg < 4; rg++)
                Osm[(i*16 + quad*4 + rg)*OSTR + h*Dh + dt*16 + m] =
                    f2bf(O[i][dt][rg]);
    __syncthreads();

    // proj GEMM: 64x128x128; wave h covers out cols [h*32, h*32+32)
    f32x4 pacc[4][2] = {};
    #pragma unroll
    for (int s = 0; s < 4; s++){
        bf16x8 pa[4], pbk[2];
        #pragma unroll
        for (int i = 0; i < 4; i++)
            pa[i] = *(const bf16x8*)&Osm[(i*16 + m)*OSTR + s*32 + quad*8];
        #pragma unroll
        for (int j = 0; j < 2; j++)
            pbk[j] = *(const bf16x8*)&pw[(size_t)(h*Dh + j*16 + m)*Cdim
                                         + s*32 + quad*8];
        #pragma unroll
        for (int i = 0; i < 4; i++)
            #pragma unroll
            for (int j = 0; j < 2; j++)
                pacc[i][j] = __builtin_amdgcn_mfma_f32_16x16x32_bf16(
                                 pa[i], pbk[j], pacc[i][j], 0, 0, 0);
    }
    __syncthreads();   // all Osm reads done

    // stage proj result (+bias) back into Osm
    #pragma unroll
    for (int i = 0; i < 4; i++)
        #pragma unroll
        for (int j = 0; j < 2; j++){
            int c = h*Dh + j*16 + m;
            float bia = pb[c];
            #pragma unroll
            for (int rg = 0; rg < 4; rg++)
                Osm[(i*16 + quad*4 + rg)*OSTR + c] = f2bf(pacc[i][j][rg] + bia);
        }
    __syncthreads();

    // coalesced store: 64 rows x 128 u16 = 1024 chunks of 16 B
    #pragma unroll
    for (int it = 0; it < 4; it++){
        int idx = it*256 + t;
        int r = idx >> 4, c16 = idx & 15;
        *(bf16x8*)&projout[((size_t)w*64 + r)*Cdim + c16*8] =
            *(const bf16x8*)&Osm[r*OSTR + c16*8];
    }
}

extern "C" void kernel_launch(void* const* d_in, const int* in_sizes, int n_in,
                              void* d_out, int out_size, void* d_ws, size_t ws_size,
                              hipStream_t stream) {
    const float* x     = (const float*)d_in[0];
    const float* rpb   = (const float*)d_in[1];
    const float* n1g   = (const float*)d_in[2];
    const float* n1b   = (const float*)d_in[3];
    const float* qkvw  = (const float*)d_in[4];
    const float* qkvb  = (const float*)d_in[5];
    const float* projw = (const float*)d_in[6];
    const float* projb = (const float*)d_in[7];
    const float* n2g   = (const float*)d_in[8];
    const float* n2b   = (const float*)d_in[9];
    const float* fc1w  = (const float*)d_in[10];
    const float* fc1b  = (const float*)d_in[11];
    const float* fc2w  = (const float*)d_in[12];
    const float* fc2b  = (const float*)d_in[13];
    float* out = (float*)d_out;

    if (ws_size < (size_t)230u * 1024u * 1024u) return;

    // Disjoint-lifetime layout (race-free):
    //   region        offset   size   lifetime
    //   projout       0        32M    s2 -> s3
    //   qbuf          32M      32M    s1 -> s2
    //   kbuf          64M      32M    s1 -> s2
    //   vbuf          96M      32M    s1 -> s2
    //   weights/bmt   224M     ~2M    s0 -> end
    char* ws = (char*)d_ws;
    u16*  projout = (u16*)(ws);
    u16*  qbuf    = (u16*)(ws + ((size_t)32  << 20));
    u16*  kbuf    = (u16*)(ws + ((size_t)64  << 20));
    u16*  vbuf    = (u16*)(ws + ((size_t)96  << 20));
    u16*  wb      = (u16*)(ws + ((size_t)224 << 20));
    u16*  qkvw_b  = wb;                // 49152
    u16*  projw_b = wb + 49152;        // 16384
    u16*  fc1w_b  = wb + 65536;        // 65536
    u16*  fc2w_b  = wb + 131072;       // 65536
    float* bmt    = (float*)(ws + ((size_t)225 << 20)); // 256 KiB

    // 0. weight conversions + bias/mask table
    cvt_kernel<<<(49152+255)/256, 256, 0, stream>>>(qkvw, qkvw_b, 49152);
    cvt_kernel<<<(16384+255)/256, 256, 0, stream>>>(projw, projw_b, 16384);
    cvt_kernel<<<(65536+255)/256, 256, 0, stream>>>(fc1w, fc1w_b, 65536);
    cvt_kernel<<<(65536+255)/256, 256, 0, stream>>>(fc2w, fc2w_b, 65536);
    bm_kernel<<<256, 256, 0, stream>>>(rpb, bmt);

    // 1. fused LN1 + QKV GEMM (XCD-aware 1-D grid: 3 which-blocks/tile on same XCD)
    ln1qkv_kernel<<<3072, 256, 0, stream>>>(
        x, n1g, n1b, qkvw_b, qkvb, qbuf, kbuf, vbuf);
    // 2. fused MFMA windowed attention + proj (block = window)
    attnproj_kernel<<<WTOT, 256, 0, stream>>>(qbuf, kbuf, vbuf, bmt,
                                              projw_b, projb, projout);
    // 3. fused residual + LN2 + MLP -> out (128-row tiles, 512-thr blocks,
    //    16 waves/CU)
    mlp_kernel<<<Mrows/128, 512, 0, stream>>>(
        x, projout, n2g, n2b, fc1w_b, fc1b, fc2w_b, fc2b, out);
}